// Round 1
// baseline (3151.343 us; speedup 1.0000x reference)
//
#include <hip/hip_runtime.h>
#include <math.h>

#define MAXNORM 0.996f      // (1 - 4e-3) / sqrt(c), c = 1
#define MIN_NORM 1e-15f

__device__ __forceinline__ float artanhf_(float x) {
    x = fminf(fmaxf(x, -1.0f + 1e-7f), 1.0f - 1e-7f);
    return 0.5f * (log1pf(x) - log1pf(-x));
}

// ---------------------------------------------------------------------------
// Kernel 1: hyperbolic bias  bh = proj(expmap0(bias)),  bh[C] + y2 at bh[C]
// one wave, C = 128, 2 elems/lane
// ---------------------------------------------------------------------------
__global__ void bias_kernel(const float* __restrict__ bias, float* __restrict__ bh) {
    const int l = threadIdx.x;             // 0..63
    float b0 = bias[2 * l], b1 = bias[2 * l + 1];
    float p = b0 * b0 + b1 * b1;
    for (int m = 1; m < 64; m <<= 1) p += __shfl_xor(p, m, 64);
    float n = fmaxf(sqrtf(p), MIN_NORM);
    float sc = tanhf(n) / n;               // expmap0 scale
    float nn = tanhf(n);                   // resulting norm
    if (nn > MAXNORM) sc *= MAXNORM / nn;  // proj
    float h0 = sc * b0, h1 = sc * b1;
    bh[2 * l]     = h0;
    bh[2 * l + 1] = h1;
    float p2 = h0 * h0 + h1 * h1;
    for (int m = 1; m < 64; m <<= 1) p2 += __shfl_xor(p2, m, 64);
    if (l == 0) bh[128] = p2;              // y2 = ||bh||^2
}

// ---------------------------------------------------------------------------
// Kernel 2: fused HypLinear + logmap0
//   mx = x @ W^T ; mobius_matvec scale ; proj ; mobius_add(bh) ; proj ; logmap0
//   writes x_t [N][128] to workspace
// block = 256 threads, 32 rows/block. D=256, C=128 hardcoded.
// ---------------------------------------------------------------------------
#define RT 32
__global__ __launch_bounds__(256) void linear_kernel(
    const float* __restrict__ x, const float* __restrict__ W,
    const float* __restrict__ bh, float* __restrict__ xt, int N)
{
    __shared__ float xs[RT][256];   // 32 KB
    __shared__ float ms[RT][128];   // 16 KB
    __shared__ float bhs[128];
    __shared__ float y2s;

    const int t = threadIdx.x;
    const int row0 = blockIdx.x * RT;

    if (t < 128) bhs[t] = bh[t];
    if (t == 0) y2s = bh[128];

    // --- load x tile (coalesced float4): 2048 float4, 8 per thread ---
    #pragma unroll
    for (int i = 0; i < 8; ++i) {
        int f  = i * 256 + t;          // float4 index within tile
        int r  = f >> 6;               // 64 float4 per row
        int c4 = f & 63;
        int gr = row0 + r; if (gr >= N) gr = N - 1;
        ((float4*)xs[r])[c4] = ((const float4*)(x + (size_t)gr * 256))[c4];
    }
    __syncthreads();

    // --- GEMM: thread (j = t&127, rh = t>>7) does rows rh*16..+15, col j ---
    const int j  = t & 127;
    const int r0 = (t >> 7) * 16;
    float acc[16];
    #pragma unroll
    for (int r = 0; r < 16; ++r) acc[r] = 0.f;

    const float4* Wj = (const float4*)(W + (size_t)j * 256);
    for (int k4 = 0; k4 < 64; ++k4) {
        float4 w = Wj[k4];
        #pragma unroll
        for (int r = 0; r < 16; ++r) {
            float4 xv = ((const float4*)xs[r0 + r])[k4];   // wave-uniform broadcast
            acc[r] += xv.x * w.x + xv.y * w.y + xv.z * w.z + xv.w * w.w;
        }
    }
    #pragma unroll
    for (int r = 0; r < 16; ++r) ms[r0 + r][j] = acc[r];
    __syncthreads();

    // --- per-row epilogue: wave wv handles rows wv*8..+7, 2 cols/lane ---
    const int wv = t >> 6, l = t & 63;
    const float y2 = y2s;
    for (int rr = 0; rr < 8; ++rr) {
        int r = wv * 8 + rr;
        int grow = row0 + r;
        float m0 = ms[r][2 * l], m1 = ms[r][2 * l + 1];
        float b0 = bhs[2 * l],   b1 = bhs[2 * l + 1];
        float4 xv = ((const float4*)xs[r])[l];
        float pxx = xv.x * xv.x + xv.y * xv.y + xv.z * xv.z + xv.w * xv.w;
        float pmm = m0 * m0 + m1 * m1;
        float pmb = m0 * b0 + m1 * b1;
        for (int m = 1; m < 64; m <<= 1) {
            pxx += __shfl_xor(pxx, m, 64);
            pmm += __shfl_xor(pmm, m, 64);
            pmb += __shfl_xor(pmb, m, 64);
        }
        float x_norm  = fmaxf(sqrtf(pxx), MIN_NORM);
        float mx_norm = fmaxf(sqrtf(pmm), MIN_NORM);
        // mobius_matvec scale (zero-row case degenerates to 0 automatically)
        float rs = tanhf(mx_norm / x_norm * artanhf_(x_norm)) / mx_norm;
        // proj
        float nres = rs * mx_norm;
        float sh = (nres > MAXNORM) ? rs * (MAXNORM / nres) : rs;
        // mobius_add(h, bh):  h = sh * mx
        float x2 = sh * sh * pmm;
        float xy = sh * pmb;
        float A = 1.f + 2.f * xy + y2;
        float B = 1.f - x2;
        float den = fmaxf(1.f + 2.f * xy + x2 * y2, MIN_NORM);
        float h20 = (A * sh * m0 + B * b0) / den;
        float h21 = (A * sh * m1 + B * b1) / den;
        float p22 = h20 * h20 + h21 * h21;
        for (int m = 1; m < 64; m <<= 1) p22 += __shfl_xor(p22, m, 64);
        // proj
        float n2 = fmaxf(sqrtf(p22), MIN_NORM);
        float g = 1.f, n3 = n2;
        if (n2 > MAXNORM) { g = MAXNORM / n2; n3 = MAXNORM; }
        // logmap0
        float a = artanhf_(n3);
        float s = g * (a / fmaxf(n3, MIN_NORM));
        if (grow < N) {
            float2 o; o.x = s * h20; o.y = s * h21;
            ((float2*)(xt + (size_t)grow * 128))[l] = o;
        }
    }
}

// ---------------------------------------------------------------------------
// Kernel 3: edge scatter  agg[row] += xt[col] * w   (32 lanes/edge, float4)
// ---------------------------------------------------------------------------
__global__ __launch_bounds__(256) void scatter_kernel(
    const float* __restrict__ xt, const int* __restrict__ row,
    const int* __restrict__ col, const float* __restrict__ ew,
    float* __restrict__ agg, int E)
{
    long g = (long)blockIdx.x * blockDim.x + threadIdx.x;
    long e = g >> 5;
    int  l = (int)(g & 31);
    if (e >= E) return;
    int r = row[e], c = col[e];
    float wv = ew[e];
    float4 v = ((const float4*)(xt + (size_t)c * 128))[l];
    float* dst = agg + (size_t)r * 128 + l * 4;
    atomicAdd(dst + 0, v.x * wv);
    atomicAdd(dst + 1, v.y * wv);
    atomicAdd(dst + 2, v.z * wv);
    atomicAdd(dst + 3, v.w * wv);
}

// ---------------------------------------------------------------------------
// Kernel 4: h = proj(expmap0(agg)); h = proj(expmap0(logmap0(h)))
// wave per row, in-place on d_out
// ---------------------------------------------------------------------------
__global__ __launch_bounds__(256) void final_kernel(float* __restrict__ io, int N) {
    const int wv = threadIdx.x >> 6, l = threadIdx.x & 63;
    const int r = blockIdx.x * 4 + wv;
    if (r >= N) return;
    float2 v = ((const float2*)(io + (size_t)r * 128))[l];
    float p = v.x * v.x + v.y * v.y;
    for (int m = 1; m < 64; m <<= 1) p += __shfl_xor(p, m, 64);
    // expmap0
    float un = fmaxf(sqrtf(p), MIN_NORM);
    float th = tanhf(un);
    float s1 = th / un;
    float n1 = th;
    if (n1 > MAXNORM) { s1 *= MAXNORM / n1; n1 = MAXNORM; }   // proj
    // logmap0
    float a  = artanhf_(n1);
    float s2 = a / fmaxf(n1, MIN_NORM);
    // expmap0 (||u2|| = a)
    float ua = fmaxf(a, MIN_NORM);
    float t3 = tanhf(ua);
    float s3 = t3 / ua;
    float s4 = (t3 > MAXNORM) ? MAXNORM / t3 : 1.f;           // proj
    float s = s1 * s2 * s3 * s4;
    float2 o; o.x = s * v.x; o.y = s * v.y;
    ((float2*)(io + (size_t)r * 128))[l] = o;
}

// ---------------------------------------------------------------------------
extern "C" void kernel_launch(void* const* d_in, const int* in_sizes, int n_in,
                              void* d_out, int out_size, void* d_ws, size_t ws_size,
                              hipStream_t stream) {
    const float* x    = (const float*)d_in[0];
    const int*   ei   = (const int*)d_in[1];
    const float* ew   = (const float*)d_in[2];
    const float* W    = (const float*)d_in[3];
    const float* bias = (const float*)d_in[4];

    const int N = in_sizes[0] / 256;
    const int E = in_sizes[2];
    float* out = (float*)d_out;
    float* ws  = (float*)d_ws;
    float* bh  = ws;              // 129 floats
    float* xt  = ws + 256;        // N*128 floats (16B aligned)

    bias_kernel<<<1, 64, 0, stream>>>(bias, bh);
    linear_kernel<<<(N + RT - 1) / RT, 256, 0, stream>>>(x, W, bh, xt, N);
    hipMemsetAsync(out, 0, (size_t)N * 128 * sizeof(float), stream);
    long threads = (long)E * 32;
    scatter_kernel<<<(unsigned)((threads + 255) / 256), 256, 0, stream>>>(
        xt, ei, ei + E, ew, out, E);
    final_kernel<<<(N + 3) / 4, 256, 0, stream>>>(out, N);
}

// Round 3
// 708.142 us; speedup vs baseline: 4.4502x; 4.4502x over previous
//
#include <hip/hip_runtime.h>
#include <math.h>

#define MAXNORM 0.996f      // (1 - 4e-3) / sqrt(c), c = 1
#define MIN_NORM 1e-15f

__device__ __forceinline__ float artanhf_(float x) {
    x = fminf(fmaxf(x, -1.0f + 1e-7f), 1.0f - 1e-7f);
    return 0.5f * (log1pf(x) - log1pf(-x));
}

// ---------------------------------------------------------------------------
// Kernel 1: hyperbolic bias  bh = proj(expmap0(bias)),  bh[C] + y2 at bh[C]
// ---------------------------------------------------------------------------
__global__ void bias_kernel(const float* __restrict__ bias, float* __restrict__ bh) {
    const int l = threadIdx.x;             // 0..63
    float b0 = bias[2 * l], b1 = bias[2 * l + 1];
    float p = b0 * b0 + b1 * b1;
    for (int m = 1; m < 64; m <<= 1) p += __shfl_xor(p, m, 64);
    float n = fmaxf(sqrtf(p), MIN_NORM);
    float sc = tanhf(n) / n;               // expmap0 scale
    float nn = tanhf(n);                   // resulting norm
    if (nn > MAXNORM) sc *= MAXNORM / nn;  // proj
    float h0 = sc * b0, h1 = sc * b1;
    bh[2 * l]     = h0;
    bh[2 * l + 1] = h1;
    float p2 = h0 * h0 + h1 * h1;
    for (int m = 1; m < 64; m <<= 1) p2 += __shfl_xor(p2, m, 64);
    if (l == 0) bh[128] = p2;              // y2 = ||bh||^2
}

// ---------------------------------------------------------------------------
// Kernel 2: fused HypLinear + logmap0 -> xt [N][128]
// ---------------------------------------------------------------------------
#define RT 32
__global__ __launch_bounds__(256) void linear_kernel(
    const float* __restrict__ x, const float* __restrict__ W,
    const float* __restrict__ bh, float* __restrict__ xt, int N)
{
    __shared__ float xs[RT][256];   // 32 KB
    __shared__ float ms[RT][128];   // 16 KB
    __shared__ float bhs[128];
    __shared__ float y2s;

    const int t = threadIdx.x;
    const int row0 = blockIdx.x * RT;

    if (t < 128) bhs[t] = bh[t];
    if (t == 0) y2s = bh[128];

    #pragma unroll
    for (int i = 0; i < 8; ++i) {
        int f  = i * 256 + t;
        int r  = f >> 6;
        int c4 = f & 63;
        int gr = row0 + r; if (gr >= N) gr = N - 1;
        ((float4*)xs[r])[c4] = ((const float4*)(x + (size_t)gr * 256))[c4];
    }
    __syncthreads();

    const int j  = t & 127;
    const int r0 = (t >> 7) * 16;
    float acc[16];
    #pragma unroll
    for (int r = 0; r < 16; ++r) acc[r] = 0.f;

    const float4* Wj = (const float4*)(W + (size_t)j * 256);
    for (int k4 = 0; k4 < 64; ++k4) {
        float4 w = Wj[k4];
        #pragma unroll
        for (int r = 0; r < 16; ++r) {
            float4 xv = ((const float4*)xs[r0 + r])[k4];
            acc[r] += xv.x * w.x + xv.y * w.y + xv.z * w.z + xv.w * w.w;
        }
    }
    #pragma unroll
    for (int r = 0; r < 16; ++r) ms[r0 + r][j] = acc[r];
    __syncthreads();

    const int wv = t >> 6, l = t & 63;
    const float y2 = y2s;
    for (int rr = 0; rr < 8; ++rr) {
        int r = wv * 8 + rr;
        int grow = row0 + r;
        float m0 = ms[r][2 * l], m1 = ms[r][2 * l + 1];
        float b0 = bhs[2 * l],   b1 = bhs[2 * l + 1];
        float4 xv = ((const float4*)xs[r])[l];
        float pxx = xv.x * xv.x + xv.y * xv.y + xv.z * xv.z + xv.w * xv.w;
        float pmm = m0 * m0 + m1 * m1;
        float pmb = m0 * b0 + m1 * b1;
        for (int m = 1; m < 64; m <<= 1) {
            pxx += __shfl_xor(pxx, m, 64);
            pmm += __shfl_xor(pmm, m, 64);
            pmb += __shfl_xor(pmb, m, 64);
        }
        float x_norm  = fmaxf(sqrtf(pxx), MIN_NORM);
        float mx_norm = fmaxf(sqrtf(pmm), MIN_NORM);
        float rs = tanhf(mx_norm / x_norm * artanhf_(x_norm)) / mx_norm;
        float nres = rs * mx_norm;
        float sh = (nres > MAXNORM) ? rs * (MAXNORM / nres) : rs;
        float x2 = sh * sh * pmm;
        float xy = sh * pmb;
        float A = 1.f + 2.f * xy + y2;
        float B = 1.f - x2;
        float den = fmaxf(1.f + 2.f * xy + x2 * y2, MIN_NORM);
        float h20 = (A * sh * m0 + B * b0) / den;
        float h21 = (A * sh * m1 + B * b1) / den;
        float p22 = h20 * h20 + h21 * h21;
        for (int m = 1; m < 64; m <<= 1) p22 += __shfl_xor(p22, m, 64);
        float n2 = fmaxf(sqrtf(p22), MIN_NORM);
        float g = 1.f, n3 = n2;
        if (n2 > MAXNORM) { g = MAXNORM / n2; n3 = MAXNORM; }
        float a = artanhf_(n3);
        float s = g * (a / fmaxf(n3, MIN_NORM));
        if (grow < N) {
            float2 o; o.x = s * h20; o.y = s * h21;
            ((float2*)(xt + (size_t)grow * 128))[l] = o;
        }
    }
}

// ---------------------------------------------------------------------------
// CSR build: count -> scan -> fill
// ---------------------------------------------------------------------------
__global__ __launch_bounds__(256) void count_kernel(
    const int* __restrict__ row, int* __restrict__ cnt, int E)
{
    int e = blockIdx.x * 256 + threadIdx.x;
    if (e < E) atomicAdd(&cnt[row[e]], 1);
}

// 1024 elements per block, 256 threads, 4/thread
__global__ __launch_bounds__(256) void scan1_kernel(
    const int* __restrict__ cnt, int* __restrict__ rowptr,
    int* __restrict__ bsum, int N)
{
    __shared__ int s[256];
    const int t = threadIdx.x;
    const int base = blockIdx.x * 1024 + t * 4;
    int v0 = (base + 0 < N) ? cnt[base + 0] : 0;
    int v1 = (base + 1 < N) ? cnt[base + 1] : 0;
    int v2 = (base + 2 < N) ? cnt[base + 2] : 0;
    int v3 = (base + 3 < N) ? cnt[base + 3] : 0;
    int tot = v0 + v1 + v2 + v3;
    s[t] = tot;
    __syncthreads();
    for (int off = 1; off < 256; off <<= 1) {
        int o = (t >= off) ? s[t - off] : 0;
        __syncthreads();
        s[t] += o;
        __syncthreads();
    }
    int excl = s[t] - tot;   // exclusive prefix of this thread's 4-group
    if (base + 0 < N) rowptr[base + 0] = excl;
    if (base + 1 < N) rowptr[base + 1] = excl + v0;
    if (base + 2 < N) rowptr[base + 2] = excl + v0 + v1;
    if (base + 3 < N) rowptr[base + 3] = excl + v0 + v1 + v2;
    if (t == 255) bsum[blockIdx.x] = s[255];
}

// single block scans block sums (nb <= 256)
__global__ __launch_bounds__(256) void scan2_kernel(int* __restrict__ bsum, int nb)
{
    __shared__ int s[256];
    const int t = threadIdx.x;
    int v = (t < nb) ? bsum[t] : 0;
    s[t] = v;
    __syncthreads();
    for (int off = 1; off < 256; off <<= 1) {
        int o = (t >= off) ? s[t - off] : 0;
        __syncthreads();
        s[t] += o;
        __syncthreads();
    }
    if (t < nb) bsum[t] = s[t] - v;   // exclusive
}

__global__ __launch_bounds__(256) void scan3_kernel(
    int* __restrict__ rowptr, int* __restrict__ cursor,
    const int* __restrict__ bsum, int N, int E)
{
    int i = blockIdx.x * 256 + threadIdx.x;
    if (i < N) {
        int v = rowptr[i] + bsum[i >> 10];
        rowptr[i] = v;
        cursor[i] = v;
    }
    if (i == 0) rowptr[N] = E;
}

__global__ __launch_bounds__(256) void fill_kernel(
    const int* __restrict__ row, const int* __restrict__ col,
    const float* __restrict__ ew, int* __restrict__ cursor,
    int* __restrict__ csr_col, float* __restrict__ csr_w, int E)
{
    int e = blockIdx.x * 256 + threadIdx.x;
    if (e >= E) return;
    int pos = atomicAdd(&cursor[row[e]], 1);
    csr_col[pos] = col[e];
    csr_w[pos]   = ew[e];
}

// ---------------------------------------------------------------------------
// Gather: one wave per destination row; accumulate in registers; fuse
// expmap0 -> proj -> logmap0 -> expmap0 -> proj; write d_out directly.
// ---------------------------------------------------------------------------
__global__ __launch_bounds__(256) void gather_kernel(
    const float* __restrict__ xt, const int* __restrict__ rowptr,
    const int* __restrict__ csr_col, const float* __restrict__ csr_w,
    float* __restrict__ out, int N)
{
    const int wv = threadIdx.x >> 6, l = threadIdx.x & 63;
    const int r = blockIdx.x * 4 + wv;
    if (r >= N) return;
    const int beg = rowptr[r], end = rowptr[r + 1];
    float a0 = 0.f, a1 = 0.f;
    for (int base = beg; base < end; base += 64) {
        int cn = end - base; if (cn > 64) cn = 64;
        int   cl = 0; float wl = 0.f;
        if (base + l < end) { cl = csr_col[base + l]; wl = csr_w[base + l]; }
        for (int jj = 0; jj < cn; ++jj) {
            int   c = __shfl(cl, jj, 64);
            float w = __shfl(wl, jj, 64);
            float2 v = ((const float2*)(xt + (size_t)c * 128))[l];
            a0 = fmaf(w, v.x, a0);
            a1 = fmaf(w, v.y, a1);
        }
    }
    float p = a0 * a0 + a1 * a1;
    for (int m = 1; m < 64; m <<= 1) p += __shfl_xor(p, m, 64);
    // expmap0
    float un = fmaxf(sqrtf(p), MIN_NORM);
    float th = tanhf(un);
    float s1 = th / un;
    float n1 = th;
    if (n1 > MAXNORM) { s1 *= MAXNORM / n1; n1 = MAXNORM; }   // proj
    // logmap0
    float a  = artanhf_(n1);
    float s2 = a / fmaxf(n1, MIN_NORM);
    // expmap0 (||u2|| = a)
    float ua = fmaxf(a, MIN_NORM);
    float t3 = tanhf(ua);
    float s3 = t3 / ua;
    float s4 = (t3 > MAXNORM) ? MAXNORM / t3 : 1.f;           // proj
    float s = s1 * s2 * s3 * s4;
    float2 o; o.x = s * a0; o.y = s * a1;
    ((float2*)(out + (size_t)r * 128))[l] = o;
}

// ---------------------------------------------------------------------------
// Fallback path (ws too small): atomic scatter + final, as round 1
// ---------------------------------------------------------------------------
__global__ __launch_bounds__(256) void scatter_kernel(
    const float* __restrict__ xt, const int* __restrict__ row,
    const int* __restrict__ col, const float* __restrict__ ew,
    float* __restrict__ agg, int E)
{
    long g = (long)blockIdx.x * blockDim.x + threadIdx.x;
    long e = g >> 5;
    int  l = (int)(g & 31);
    if (e >= E) return;
    int r = row[e], c = col[e];
    float wv = ew[e];
    float4 v = ((const float4*)(xt + (size_t)c * 128))[l];
    float* dst = agg + (size_t)r * 128 + l * 4;
    atomicAdd(dst + 0, v.x * wv);
    atomicAdd(dst + 1, v.y * wv);
    atomicAdd(dst + 2, v.z * wv);
    atomicAdd(dst + 3, v.w * wv);
}

__global__ __launch_bounds__(256) void final_kernel(float* __restrict__ io, int N) {
    const int wv = threadIdx.x >> 6, l = threadIdx.x & 63;
    const int r = blockIdx.x * 4 + wv;
    if (r >= N) return;
    float2 v = ((const float2*)(io + (size_t)r * 128))[l];
    float p = v.x * v.x + v.y * v.y;
    for (int m = 1; m < 64; m <<= 1) p += __shfl_xor(p, m, 64);
    float un = fmaxf(sqrtf(p), MIN_NORM);
    float th = tanhf(un);
    float s1 = th / un;
    float n1 = th;
    if (n1 > MAXNORM) { s1 *= MAXNORM / n1; n1 = MAXNORM; }
    float a  = artanhf_(n1);
    float s2 = a / fmaxf(n1, MIN_NORM);
    float ua = fmaxf(a, MIN_NORM);
    float t3 = tanhf(ua);
    float s3 = t3 / ua;
    float s4 = (t3 > MAXNORM) ? MAXNORM / t3 : 1.f;
    float s = s1 * s2 * s3 * s4;
    float2 o; o.x = s * v.x; o.y = s * v.y;
    ((float2*)(io + (size_t)r * 128))[l] = o;
}

// ---------------------------------------------------------------------------
extern "C" void kernel_launch(void* const* d_in, const int* in_sizes, int n_in,
                              void* d_out, int out_size, void* d_ws, size_t ws_size,
                              hipStream_t stream) {
    const float* x    = (const float*)d_in[0];
    const int*   ei   = (const int*)d_in[1];
    const float* ew   = (const float*)d_in[2];
    const float* W    = (const float*)d_in[3];
    const float* bias = (const float*)d_in[4];

    const int N = in_sizes[0] / 256;
    const int E = in_sizes[2];
    float* out = (float*)d_out;
    char*  ws  = (char*)d_ws;

    // workspace layout (16B aligned chunks)
    size_t off = 0;
    float* bh = (float*)(ws + off);           off += 256 * sizeof(float);
    float* xt = (float*)(ws + off);           off += (size_t)N * 128 * sizeof(float);
    int* rowptr = (int*)(ws + off);           off += ((size_t)N + 16) * sizeof(int);
    int* cursor = (int*)(ws + off);           off += (size_t)N * sizeof(int);
    int* bsum   = (int*)(ws + off);           off += 4096 * sizeof(int);
    int* csr_col = (int*)(ws + off);          off += (size_t)E * sizeof(int);
    float* csr_w = (float*)(ws + off);        off += (size_t)E * sizeof(float);
    const size_t need = off;

    bias_kernel<<<1, 64, 0, stream>>>(bias, bh);
    linear_kernel<<<(N + RT - 1) / RT, 256, 0, stream>>>(x, W, bh, xt, N);

    if (ws_size >= need) {
        // cnt lives in rowptr region; zero it
        hipMemsetAsync(rowptr, 0, (size_t)N * sizeof(int), stream);
        const int nb = (N + 1023) / 1024;     // <= 256 for N <= 262144
        count_kernel<<<(E + 255) / 256, 256, 0, stream>>>(ei, rowptr, E);
        scan1_kernel<<<nb, 256, 0, stream>>>(rowptr, rowptr, bsum, N);
        scan2_kernel<<<1, 256, 0, stream>>>(bsum, nb);
        scan3_kernel<<<(N + 255) / 256, 256, 0, stream>>>(rowptr, cursor, bsum, N, E);
        fill_kernel<<<(E + 255) / 256, 256, 0, stream>>>(
            ei, ei + E, ew, cursor, csr_col, csr_w, E);
        gather_kernel<<<(N + 3) / 4, 256, 0, stream>>>(
            xt, rowptr, csr_col, csr_w, out, N);
    } else {
        hipMemsetAsync(out, 0, (size_t)N * 128 * sizeof(float), stream);
        long threads = (long)E * 32;
        scatter_kernel<<<(unsigned)((threads + 255) / 256), 256, 0, stream>>>(
            xt, ei, ei + E, ew, out, E);
        final_kernel<<<(N + 3) / 4, 256, 0, stream>>>(out, N);
    }
}

// Round 5
// 544.506 us; speedup vs baseline: 5.7875x; 1.3005x over previous
//
#include <hip/hip_runtime.h>
#include <math.h>

#define MAXNORM 0.996f      // (1 - 4e-3) / sqrt(c), c = 1
#define MIN_NORM 1e-15f

typedef __attribute__((ext_vector_type(8))) short short8;
typedef __attribute__((ext_vector_type(4))) float f32x4;

__device__ __forceinline__ float artanhf_(float x) {
    x = fminf(fmaxf(x, -1.0f + 1e-7f), 1.0f - 1e-7f);
    return 0.5f * (log1pf(x) - log1pf(-x));
}

__device__ __forceinline__ unsigned short f2bf(float f) {
    unsigned u = __float_as_uint(f);
    unsigned r = u + 0x7fffu + ((u >> 16) & 1u);   // round-to-nearest-even
    return (unsigned short)(r >> 16);
}

// ---------------------------------------------------------------------------
// Kernel: hyperbolic bias  bh = proj(expmap0(bias)), y2 stored at bh[128]
// ---------------------------------------------------------------------------
__global__ void bias_kernel(const float* __restrict__ bias, float* __restrict__ bh) {
    const int l = threadIdx.x;             // 0..63
    float b0 = bias[2 * l], b1 = bias[2 * l + 1];
    float p = b0 * b0 + b1 * b1;
    for (int m = 1; m < 64; m <<= 1) p += __shfl_xor(p, m, 64);
    float n = fmaxf(sqrtf(p), MIN_NORM);
    float sc = tanhf(n) / n;
    float nn = tanhf(n);
    if (nn > MAXNORM) sc *= MAXNORM / nn;
    float h0 = sc * b0, h1 = sc * b1;
    bh[2 * l]     = h0;
    bh[2 * l + 1] = h1;
    float p2 = h0 * h0 + h1 * h1;
    for (int m = 1; m < 64; m <<= 1) p2 += __shfl_xor(p2, m, 64);
    if (l == 0) bh[128] = p2;
}

// ---------------------------------------------------------------------------
// prep_x: x f32 -> xb bf16, xn[r] = ||x_r||^2 (f32, exact). One wave per row.
// ---------------------------------------------------------------------------
__global__ __launch_bounds__(256) void prep_x(
    const float* __restrict__ x, unsigned short* __restrict__ xb,
    float* __restrict__ xn, int N)
{
    const int wv = threadIdx.x >> 6, l = threadIdx.x & 63;
    for (int r = blockIdx.x * 4 + wv; r < N; r += gridDim.x * 4) {
        float4 v = ((const float4*)(x + (size_t)r * 256))[l];
        float p = v.x * v.x + v.y * v.y + v.z * v.z + v.w * v.w;
        for (int m = 1; m < 64; m <<= 1) p += __shfl_xor(p, m, 64);
        ushort4 o;
        o.x = f2bf(v.x); o.y = f2bf(v.y); o.z = f2bf(v.z); o.w = f2bf(v.w);
        ((ushort4*)(xb + (size_t)r * 256))[l] = o;
        if (l == 0) xn[r] = p;
    }
}

// prep_w: W f32 [128][256] -> bf16 (exactly 32768 elements, 128 blocks)
__global__ __launch_bounds__(256) void prep_w(
    const float* __restrict__ W, unsigned short* __restrict__ wb)
{
    int i = blockIdx.x * 256 + threadIdx.x;
    wb[i] = f2bf(W[i]);
}

// ---------------------------------------------------------------------------
// linear_mfma: fused HypLinear + logmap0 via MFMA bf16.
//   Block = 256 thr (4 waves), tile 32 rows x 128 cols, K = 256.
//   Wave w owns cols [w*32, w*32+32). No LDS staging for operands:
//   A-frags from global bf16 (L1-shared), B-frags preloaded in VGPRs.
//   Epilogue: xt = alpha[row]*m + beta[row]*bh[col] (closed-form ||h2||^2).
// ---------------------------------------------------------------------------
__global__ __launch_bounds__(256) void linear_mfma(
    const unsigned short* __restrict__ xb, const unsigned short* __restrict__ wb,
    const float* __restrict__ xn, const float* __restrict__ bh,
    float* __restrict__ xt, int N)
{
    __shared__ float part[4][32][2];
    __shared__ float ab[32][2];
    __shared__ float y2s;

    const int t = threadIdx.x;
    const int w = t >> 6, l = t & 63;
    const int lo = l & 15, hi = l >> 4;
    const int row0 = blockIdx.x * 32;
    if (t == 0) y2s = bh[128];

    // B fragments: col = w*32 + cg*16 + lo, k = ks*32 + hi*8 + e
    short8 bf[2][8];
    #pragma unroll
    for (int cg = 0; cg < 2; ++cg) {
        const unsigned short* bp = wb + (size_t)(w * 32 + cg * 16 + lo) * 256 + hi * 8;
        #pragma unroll
        for (int ks = 0; ks < 8; ++ks)
            bf[cg][ks] = *(const short8*)(bp + ks * 32);
    }

    int ra0 = row0 + lo;      if (ra0 >= N) ra0 = N - 1;
    int ra1 = row0 + 16 + lo; if (ra1 >= N) ra1 = N - 1;
    const unsigned short* ap0 = xb + (size_t)ra0 * 256 + hi * 8;
    const unsigned short* ap1 = xb + (size_t)ra1 * 256 + hi * 8;

    f32x4 acc[2][2] = {};
    #pragma unroll
    for (int ks = 0; ks < 8; ++ks) {
        short8 a0 = *(const short8*)(ap0 + ks * 32);
        short8 a1 = *(const short8*)(ap1 + ks * 32);
        acc[0][0] = __builtin_amdgcn_mfma_f32_16x16x32_bf16(a0, bf[0][ks], acc[0][0], 0, 0, 0);
        acc[0][1] = __builtin_amdgcn_mfma_f32_16x16x32_bf16(a0, bf[1][ks], acc[0][1], 0, 0, 0);
        acc[1][0] = __builtin_amdgcn_mfma_f32_16x16x32_bf16(a1, bf[0][ks], acc[1][0], 0, 0, 0);
        acc[1][1] = __builtin_amdgcn_mfma_f32_16x16x32_bf16(a1, bf[1][ks], acc[1][1], 0, 0, 0);
    }

    // per-lane bh values for this wave's two col-fragments
    float bhv0 = bh[w * 32 + lo];
    float bhv1 = bh[w * 32 + 16 + lo];

    // per-row partial sums (this wave's 32 cols), 16-lane reduce
    float spm[2][4], spb[2][4];
    #pragma unroll
    for (int rg = 0; rg < 2; ++rg)
    #pragma unroll
    for (int r = 0; r < 4; ++r) {
        float m0 = acc[rg][0][r], m1 = acc[rg][1][r];
        float pm = m0 * m0 + m1 * m1;
        float pb = m0 * bhv0 + m1 * bhv1;
        #pragma unroll
        for (int mk = 1; mk < 16; mk <<= 1) {
            pm += __shfl_xor(pm, mk, 64);
            pb += __shfl_xor(pb, mk, 64);
        }
        spm[rg][r] = pm; spb[rg][r] = pb;
    }
    if (lo == 0) {
        #pragma unroll
        for (int rg = 0; rg < 2; ++rg)
        #pragma unroll
        for (int r = 0; r < 4; ++r) {
            int row = rg * 16 + hi * 4 + r;
            part[w][row][0] = spm[rg][r];
            part[w][row][1] = spb[rg][r];
        }
    }
    __syncthreads();

    if (t < 32) {
        const int row = t;
        float pmm = part[0][row][0] + part[1][row][0] + part[2][row][0] + part[3][row][0];
        float pmb = part[0][row][1] + part[1][row][1] + part[2][row][1] + part[3][row][1];
        int grow = row0 + row; if (grow >= N) grow = N - 1;
        float pxx = xn[grow];
        float y2 = y2s;
        float x_norm  = fmaxf(sqrtf(pxx), MIN_NORM);
        float mx_norm = fmaxf(sqrtf(pmm), MIN_NORM);
        float rs = tanhf(mx_norm / x_norm * artanhf_(x_norm)) / mx_norm;
        float nres = rs * mx_norm;
        float sh = (nres > MAXNORM) ? rs * (MAXNORM / nres) : rs;
        float x2 = sh * sh * pmm;
        float xy = sh * pmb;
        float A_ = 1.f + 2.f * xy + y2;
        float B_ = 1.f - x2;
        float den = fmaxf(1.f + 2.f * xy + x2 * y2, MIN_NORM);
        // ||h2||^2 in closed form: no second data reduction needed
        float p22 = (A_ * A_ * sh * sh * pmm + 2.f * A_ * sh * B_ * pmb + B_ * B_ * y2)
                    / (den * den);
        float n2 = fmaxf(sqrtf(p22), MIN_NORM);
        float g = 1.f, n3 = n2;
        if (n2 > MAXNORM) { g = MAXNORM / n2; n3 = MAXNORM; }
        float a = artanhf_(n3);
        float s = g * (a / fmaxf(n3, MIN_NORM));
        ab[row][0] = s * A_ * sh / den;   // alpha
        ab[row][1] = s * B_ / den;        // beta
    }
    __syncthreads();

    #pragma unroll
    for (int rg = 0; rg < 2; ++rg)
    #pragma unroll
    for (int r = 0; r < 4; ++r) {
        int row = rg * 16 + hi * 4 + r;
        int grow = row0 + row;
        if (grow < N) {
            float alpha = ab[row][0], beta = ab[row][1];
            float* dst = xt + (size_t)grow * 128 + w * 32 + lo;
            dst[0]  = alpha * acc[rg][0][r] + beta * bhv0;
            dst[16] = alpha * acc[rg][1][r] + beta * bhv1;
        }
    }
}

// ---------------------------------------------------------------------------
// CSR build: count -> scan -> fill
// ---------------------------------------------------------------------------
__global__ __launch_bounds__(256) void count_kernel(
    const int* __restrict__ row, int* __restrict__ cnt, int E)
{
    int e = blockIdx.x * 256 + threadIdx.x;
    if (e < E) atomicAdd(&cnt[row[e]], 1);
}

__global__ __launch_bounds__(256) void scan1_kernel(
    const int* __restrict__ cnt, int* __restrict__ rowptr,
    int* __restrict__ bsum, int N)
{
    __shared__ int s[256];
    const int t = threadIdx.x;
    const int base = blockIdx.x * 1024 + t * 4;
    int v0 = (base + 0 < N) ? cnt[base + 0] : 0;
    int v1 = (base + 1 < N) ? cnt[base + 1] : 0;
    int v2 = (base + 2 < N) ? cnt[base + 2] : 0;
    int v3 = (base + 3 < N) ? cnt[base + 3] : 0;
    int tot = v0 + v1 + v2 + v3;
    s[t] = tot;
    __syncthreads();
    for (int off = 1; off < 256; off <<= 1) {
        int o = (t >= off) ? s[t - off] : 0;
        __syncthreads();
        s[t] += o;
        __syncthreads();
    }
    int excl = s[t] - tot;
    if (base + 0 < N) rowptr[base + 0] = excl;
    if (base + 1 < N) rowptr[base + 1] = excl + v0;
    if (base + 2 < N) rowptr[base + 2] = excl + v0 + v1;
    if (base + 3 < N) rowptr[base + 3] = excl + v0 + v1 + v2;
    if (t == 255) bsum[blockIdx.x] = s[255];
}

__global__ __launch_bounds__(256) void scan2_kernel(int* __restrict__ bsum, int nb)
{
    __shared__ int s[256];
    const int t = threadIdx.x;
    int v = (t < nb) ? bsum[t] : 0;
    s[t] = v;
    __syncthreads();
    for (int off = 1; off < 256; off <<= 1) {
        int o = (t >= off) ? s[t - off] : 0;
        __syncthreads();
        s[t] += o;
        __syncthreads();
    }
    if (t < nb) bsum[t] = s[t] - v;
}

__global__ __launch_bounds__(256) void scan3_kernel(
    int* __restrict__ rowptr, int* __restrict__ cursor,
    const int* __restrict__ bsum, int N, int E)
{
    int i = blockIdx.x * 256 + threadIdx.x;
    if (i < N) {
        int v = rowptr[i] + bsum[i >> 10];
        rowptr[i] = v;
        cursor[i] = v;
    }
    if (i == 0) rowptr[N] = E;
}

__global__ __launch_bounds__(256) void fill_kernel(
    const int* __restrict__ row, const int* __restrict__ col,
    const float* __restrict__ ew, int* __restrict__ cursor,
    int* __restrict__ csr_col, float* __restrict__ csr_w, int E)
{
    int e = blockIdx.x * 256 + threadIdx.x;
    if (e >= E) return;
    int pos = atomicAdd(&cursor[row[e]], 1);
    csr_col[pos] = col[e];
    csr_w[pos]   = ew[e];
}

// ---------------------------------------------------------------------------
// Gather: one wave per destination row; fused final chain; writes d_out.
// ---------------------------------------------------------------------------
__global__ __launch_bounds__(256) void gather_kernel(
    const float* __restrict__ xt, const int* __restrict__ rowptr,
    const int* __restrict__ csr_col, const float* __restrict__ csr_w,
    float* __restrict__ out, int N)
{
    const int wv = threadIdx.x >> 6, l = threadIdx.x & 63;
    const int r = blockIdx.x * 4 + wv;
    if (r >= N) return;
    const int beg = rowptr[r], end = rowptr[r + 1];
    float a0 = 0.f, a1 = 0.f;
    for (int base = beg; base < end; base += 64) {
        int cn = end - base; if (cn > 64) cn = 64;
        int   cl = 0; float wl = 0.f;
        if (base + l < end) { cl = csr_col[base + l]; wl = csr_w[base + l]; }
        for (int jj = 0; jj < cn; ++jj) {
            int   c = __shfl(cl, jj, 64);
            float w = __shfl(wl, jj, 64);
            float2 v = ((const float2*)(xt + (size_t)c * 128))[l];
            a0 = fmaf(w, v.x, a0);
            a1 = fmaf(w, v.y, a1);
        }
    }
    float p = a0 * a0 + a1 * a1;
    for (int m = 1; m < 64; m <<= 1) p += __shfl_xor(p, m, 64);
    float un = fmaxf(sqrtf(p), MIN_NORM);
    float th = tanhf(un);
    float s1 = th / un;
    float n1 = th;
    if (n1 > MAXNORM) { s1 *= MAXNORM / n1; n1 = MAXNORM; }
    float a  = artanhf_(n1);
    float s2 = a / fmaxf(n1, MIN_NORM);
    float ua = fmaxf(a, MIN_NORM);
    float t3 = tanhf(ua);
    float s3 = t3 / ua;
    float s4 = (t3 > MAXNORM) ? MAXNORM / t3 : 1.f;
    float s = s1 * s2 * s3 * s4;
    float2 o; o.x = s * a0; o.y = s * a1;
    ((float2*)(out + (size_t)r * 128))[l] = o;
}

// ---------------------------------------------------------------------------
// Fallback: round-3 f32 linear (if ws too small for bf16 buffers)
// ---------------------------------------------------------------------------
#define RT 32
__global__ __launch_bounds__(256) void linear_kernel(
    const float* __restrict__ x, const float* __restrict__ W,
    const float* __restrict__ bh, float* __restrict__ xt, int N)
{
    __shared__ float xs[RT][256];
    __shared__ float ms[RT][128];
    __shared__ float bhs[128];
    __shared__ float y2s;

    const int t = threadIdx.x;
    const int row0 = blockIdx.x * RT;

    if (t < 128) bhs[t] = bh[t];
    if (t == 0) y2s = bh[128];

    #pragma unroll
    for (int i = 0; i < 8; ++i) {
        int f  = i * 256 + t;
        int r  = f >> 6;
        int c4 = f & 63;
        int gr = row0 + r; if (gr >= N) gr = N - 1;
        ((float4*)xs[r])[c4] = ((const float4*)(x + (size_t)gr * 256))[c4];
    }
    __syncthreads();

    const int j  = t & 127;
    const int r0 = (t >> 7) * 16;
    float acc[16];
    #pragma unroll
    for (int r = 0; r < 16; ++r) acc[r] = 0.f;

    const float4* Wj = (const float4*)(W + (size_t)j * 256);
    for (int k4 = 0; k4 < 64; ++k4) {
        float4 w = Wj[k4];
        #pragma unroll
        for (int r = 0; r < 16; ++r) {
            float4 xv = ((const float4*)xs[r0 + r])[k4];
            acc[r] += xv.x * w.x + xv.y * w.y + xv.z * w.z + xv.w * w.w;
        }
    }
    #pragma unroll
    for (int r = 0; r < 16; ++r) ms[r0 + r][j] = acc[r];
    __syncthreads();

    const int wv = t >> 6, l = t & 63;
    const float y2 = y2s;
    for (int rr = 0; rr < 8; ++rr) {
        int r = wv * 8 + rr;
        int grow = row0 + r;
        float m0 = ms[r][2 * l], m1 = ms[r][2 * l + 1];
        float b0 = bhs[2 * l],   b1 = bhs[2 * l + 1];
        float4 xv = ((const float4*)xs[r])[l];
        float pxx = xv.x * xv.x + xv.y * xv.y + xv.z * xv.z + xv.w * xv.w;
        float pmm = m0 * m0 + m1 * m1;
        float pmb = m0 * b0 + m1 * b1;
        for (int m = 1; m < 64; m <<= 1) {
            pxx += __shfl_xor(pxx, m, 64);
            pmm += __shfl_xor(pmm, m, 64);
            pmb += __shfl_xor(pmb, m, 64);
        }
        float x_norm  = fmaxf(sqrtf(pxx), MIN_NORM);
        float mx_norm = fmaxf(sqrtf(pmm), MIN_NORM);
        float rs = tanhf(mx_norm / x_norm * artanhf_(x_norm)) / mx_norm;
        float nres = rs * mx_norm;
        float sh = (nres > MAXNORM) ? rs * (MAXNORM / nres) : rs;
        float x2 = sh * sh * pmm;
        float xy = sh * pmb;
        float A = 1.f + 2.f * xy + y2;
        float B = 1.f - x2;
        float den = fmaxf(1.f + 2.f * xy + x2 * y2, MIN_NORM);
        float h20 = (A * sh * m0 + B * b0) / den;
        float h21 = (A * sh * m1 + B * b1) / den;
        float p22 = h20 * h20 + h21 * h21;
        for (int m = 1; m < 64; m <<= 1) p22 += __shfl_xor(p22, m, 64);
        float n2 = fmaxf(sqrtf(p22), MIN_NORM);
        float g = 1.f, n3 = n2;
        if (n2 > MAXNORM) { g = MAXNORM / n2; n3 = MAXNORM; }
        float a = artanhf_(n3);
        float s = g * (a / fmaxf(n3, MIN_NORM));
        if (grow < N) {
            float2 o; o.x = s * h20; o.y = s * h21;
            ((float2*)(xt + (size_t)grow * 128))[l] = o;
        }
    }
}

__global__ __launch_bounds__(256) void scatter_kernel(
    const float* __restrict__ xt, const int* __restrict__ row,
    const int* __restrict__ col, const float* __restrict__ ew,
    float* __restrict__ agg, int E)
{
    long g = (long)blockIdx.x * blockDim.x + threadIdx.x;
    long e = g >> 5;
    int  l = (int)(g & 31);
    if (e >= E) return;
    int r = row[e], c = col[e];
    float wv = ew[e];
    float4 v = ((const float4*)(xt + (size_t)c * 128))[l];
    float* dst = agg + (size_t)r * 128 + l * 4;
    atomicAdd(dst + 0, v.x * wv);
    atomicAdd(dst + 1, v.y * wv);
    atomicAdd(dst + 2, v.z * wv);
    atomicAdd(dst + 3, v.w * wv);
}

__global__ __launch_bounds__(256) void final_kernel(float* __restrict__ io, int N) {
    const int wv = threadIdx.x >> 6, l = threadIdx.x & 63;
    const int r = blockIdx.x * 4 + wv;
    if (r >= N) return;
    float2 v = ((const float2*)(io + (size_t)r * 128))[l];
    float p = v.x * v.x + v.y * v.y;
    for (int m = 1; m < 64; m <<= 1) p += __shfl_xor(p, m, 64);
    float un = fmaxf(sqrtf(p), MIN_NORM);
    float th = tanhf(un);
    float s1 = th / un;
    float n1 = th;
    if (n1 > MAXNORM) { s1 *= MAXNORM / n1; n1 = MAXNORM; }
    float a  = artanhf_(n1);
    float s2 = a / fmaxf(n1, MIN_NORM);
    float ua = fmaxf(a, MIN_NORM);
    float t3 = tanhf(ua);
    float s3 = t3 / ua;
    float s4 = (t3 > MAXNORM) ? MAXNORM / t3 : 1.f;
    float s = s1 * s2 * s3 * s4;
    float2 o; o.x = s * v.x; o.y = s * v.y;
    ((float2*)(io + (size_t)r * 128))[l] = o;
}

// ---------------------------------------------------------------------------
extern "C" void kernel_launch(void* const* d_in, const int* in_sizes, int n_in,
                              void* d_out, int out_size, void* d_ws, size_t ws_size,
                              hipStream_t stream) {
    const float* x    = (const float*)d_in[0];
    const int*   ei   = (const int*)d_in[1];
    const float* ew   = (const float*)d_in[2];
    const float* W    = (const float*)d_in[3];
    const float* bias = (const float*)d_in[4];

    const int N = in_sizes[0] / 256;
    const int E = in_sizes[2];
    float* out = (float*)d_out;
    char*  ws  = (char*)d_ws;

    // --- new layout (bf16 MFMA path) ---
    size_t off = 0;
    float* bh = (float*)(ws + off);            off += 256 * sizeof(float);
    float* xn = (float*)(ws + off);            off += (((size_t)N + 3) & ~3ull) * sizeof(float);
    unsigned short* xb = (unsigned short*)(ws + off); off += (size_t)N * 256 * sizeof(unsigned short);
    unsigned short* wb = (unsigned short*)(ws + off); off += 32768 * sizeof(unsigned short);
    float* xt = (float*)(ws + off);            off += (size_t)N * 128 * sizeof(float);
    int* rowptr = (int*)(ws + off);            off += ((size_t)N + 16) * sizeof(int);
    int* cursor = (int*)(ws + off);            off += (size_t)N * sizeof(int);
    int* bsum   = (int*)(ws + off);            off += 4096 * sizeof(int);
    int* csr_col = (int*)(ws + off);           off += (size_t)E * sizeof(int);
    float* csr_w = (float*)(ws + off);         off += (size_t)E * sizeof(float);
    const size_t need_new = off;

    // --- old layout (f32 fallback) ---
    size_t off2 = 0;
    float* bh2 = (float*)(ws + off2);          off2 += 256 * sizeof(float);
    float* xt2 = (float*)(ws + off2);          off2 += (size_t)N * 128 * sizeof(float);
    int* rowptr2 = (int*)(ws + off2);          off2 += ((size_t)N + 16) * sizeof(int);
    int* cursor2 = (int*)(ws + off2);          off2 += (size_t)N * sizeof(int);
    int* bsum2   = (int*)(ws + off2);          off2 += 4096 * sizeof(int);
    int* csr_col2 = (int*)(ws + off2);         off2 += (size_t)E * sizeof(int);
    float* csr_w2 = (float*)(ws + off2);       off2 += (size_t)E * sizeof(float);
    const size_t need_old = off2;

    const int nb = (N + 1023) / 1024;          // <= 256 for N <= 262144

    if (ws_size >= need_new) {
        bias_kernel<<<1, 64, 0, stream>>>(bias, bh);
        prep_w<<<128, 256, 0, stream>>>(W, wb);
        prep_x<<<2048, 256, 0, stream>>>(x, xb, xn, N);
        linear_mfma<<<(N + 31) / 32, 256, 0, stream>>>(xb, wb, xn, bh, xt, N);
        hipMemsetAsync(rowptr, 0, (size_t)N * sizeof(int), stream);
        count_kernel<<<(E + 255) / 256, 256, 0, stream>>>(ei, rowptr, E);
        scan1_kernel<<<nb, 256, 0, stream>>>(rowptr, rowptr, bsum, N);
        scan2_kernel<<<1, 256, 0, stream>>>(bsum, nb);
        scan3_kernel<<<(N + 255) / 256, 256, 0, stream>>>(rowptr, cursor, bsum, N, E);
        fill_kernel<<<(E + 255) / 256, 256, 0, stream>>>(
            ei, ei + E, ew, cursor, csr_col, csr_w, E);
        gather_kernel<<<(N + 3) / 4, 256, 0, stream>>>(
            xt, rowptr, csr_col, csr_w, out, N);
    } else if (ws_size >= need_old) {
        bias_kernel<<<1, 64, 0, stream>>>(bias, bh2);
        linear_kernel<<<(N + RT - 1) / RT, 256, 0, stream>>>(x, W, bh2, xt2, N);
        hipMemsetAsync(rowptr2, 0, (size_t)N * sizeof(int), stream);
        count_kernel<<<(E + 255) / 256, 256, 0, stream>>>(ei, rowptr2, E);
        scan1_kernel<<<nb, 256, 0, stream>>>(rowptr2, rowptr2, bsum2, N);
        scan2_kernel<<<1, 256, 0, stream>>>(bsum2, nb);
        scan3_kernel<<<(N + 255) / 256, 256, 0, stream>>>(rowptr2, cursor2, bsum2, N, E);
        fill_kernel<<<(E + 255) / 256, 256, 0, stream>>>(
            ei, ei + E, ew, cursor2, csr_col2, csr_w2, E);
        gather_kernel<<<(N + 3) / 4, 256, 0, stream>>>(
            xt2, rowptr2, csr_col2, csr_w2, out, N);
    } else {
        bias_kernel<<<1, 64, 0, stream>>>(bias, bh2);
        linear_kernel<<<(N + RT - 1) / RT, 256, 0, stream>>>(x, W, bh2, xt2, N);
        hipMemsetAsync(out, 0, (size_t)N * 128 * sizeof(float), stream);
        long threads = (long)E * 32;
        scatter_kernel<<<(unsigned)((threads + 255) / 256), 256, 0, stream>>>(
            xt2, ei, ei + E, ew, out, E);
        final_kernel<<<(N + 3) / 4, 256, 0, stream>>>(out, N);
    }
}

// Round 6
// 542.170 us; speedup vs baseline: 5.8125x; 1.0043x over previous
//
#include <hip/hip_runtime.h>
#include <math.h>

#define MAXNORM 0.996f      // (1 - 4e-3) / sqrt(c), c = 1
#define MIN_NORM 1e-15f

typedef __attribute__((ext_vector_type(8))) short short8;
typedef __attribute__((ext_vector_type(4))) float f32x4;

__device__ __forceinline__ float artanhf_(float x) {
    x = fminf(fmaxf(x, -1.0f + 1e-7f), 1.0f - 1e-7f);
    return 0.5f * (log1pf(x) - log1pf(-x));
}

__device__ __forceinline__ unsigned short f2bf(float f) {
    unsigned u = __float_as_uint(f);
    unsigned r = u + 0x7fffu + ((u >> 16) & 1u);   // round-to-nearest-even
    return (unsigned short)(r >> 16);
}

// ---------------------------------------------------------------------------
// bias: bh = proj(expmap0(bias)), y2 at bh[128]
// ---------------------------------------------------------------------------
__global__ void bias_kernel(const float* __restrict__ bias, float* __restrict__ bh) {
    const int l = threadIdx.x;             // 0..63
    float b0 = bias[2 * l], b1 = bias[2 * l + 1];
    float p = b0 * b0 + b1 * b1;
    for (int m = 1; m < 64; m <<= 1) p += __shfl_xor(p, m, 64);
    float n = fmaxf(sqrtf(p), MIN_NORM);
    float sc = tanhf(n) / n;
    float nn = tanhf(n);
    if (nn > MAXNORM) sc *= MAXNORM / nn;
    float h0 = sc * b0, h1 = sc * b1;
    bh[2 * l]     = h0;
    bh[2 * l + 1] = h1;
    float p2 = h0 * h0 + h1 * h1;
    for (int m = 1; m < 64; m <<= 1) p2 += __shfl_xor(p2, m, 64);
    if (l == 0) bh[128] = p2;
}

// prep_w: W f32 [128][256] -> bf16 (32768 elems)
__global__ __launch_bounds__(256) void prep_w(
    const float* __restrict__ W, unsigned short* __restrict__ wb)
{
    int i = blockIdx.x * 256 + threadIdx.x;
    wb[i] = f2bf(W[i]);
}

// ---------------------------------------------------------------------------
// linear_mfma: fused HypLinear + logmap0, f32 x loaded directly
// (in-register bf16 convert + in-wave ||x||^2), xt written as packed bf16.
// B-slot permutation: slot lo of frag cg carries W row (w*32 + 2*lo + cg),
// so each lane's two outputs are ADJACENT cols (2*lo, 2*lo+1) -> one uint.
// ---------------------------------------------------------------------------
__global__ __launch_bounds__(256) void linear_mfma(
    const float* __restrict__ x, const unsigned short* __restrict__ wb,
    const float* __restrict__ bh, unsigned int* __restrict__ xtb, int N)
{
    __shared__ float part[4][32][2];
    __shared__ float ab[32][2];
    __shared__ float xsum[32];
    __shared__ float y2s;

    const int t = threadIdx.x;
    const int w = t >> 6, l = t & 63;
    const int lo = l & 15, hi = l >> 4;
    const int row0 = blockIdx.x * 32;
    if (t == 0) y2s = bh[128];

    // B fragments (permuted cols): slot lo of frag cg = W row w*32 + 2*lo + cg
    short8 bf[2][8];
    #pragma unroll
    for (int cg = 0; cg < 2; ++cg) {
        const unsigned short* bp = wb + (size_t)(w * 32 + 2 * lo + cg) * 256 + hi * 8;
        #pragma unroll
        for (int ks = 0; ks < 8; ++ks)
            bf[cg][ks] = *(const short8*)(bp + ks * 32);
    }

    int ra0 = row0 + lo;      if (ra0 >= N) ra0 = N - 1;
    int ra1 = row0 + 16 + lo; if (ra1 >= N) ra1 = N - 1;
    const float* ap0 = x + (size_t)ra0 * 256 + hi * 8;
    const float* ap1 = x + (size_t)ra1 * 256 + hi * 8;

    f32x4 acc[2][2] = {};
    float p0 = 0.f, p1 = 0.f;   // partial ||x||^2 (this lane's 64 elems/row)
    #pragma unroll
    for (int ks = 0; ks < 8; ++ks) {
        float4 f00 = *(const float4*)(ap0 + ks * 32);
        float4 f01 = *(const float4*)(ap0 + ks * 32 + 4);
        float4 f10 = *(const float4*)(ap1 + ks * 32);
        float4 f11 = *(const float4*)(ap1 + ks * 32 + 4);
        p0 += f00.x*f00.x + f00.y*f00.y + f00.z*f00.z + f00.w*f00.w
            + f01.x*f01.x + f01.y*f01.y + f01.z*f01.z + f01.w*f01.w;
        p1 += f10.x*f10.x + f10.y*f10.y + f10.z*f10.z + f10.w*f10.w
            + f11.x*f11.x + f11.y*f11.y + f11.z*f11.z + f11.w*f11.w;
        short8 a0, a1;
        a0[0]=(short)f2bf(f00.x); a0[1]=(short)f2bf(f00.y);
        a0[2]=(short)f2bf(f00.z); a0[3]=(short)f2bf(f00.w);
        a0[4]=(short)f2bf(f01.x); a0[5]=(short)f2bf(f01.y);
        a0[6]=(short)f2bf(f01.z); a0[7]=(short)f2bf(f01.w);
        a1[0]=(short)f2bf(f10.x); a1[1]=(short)f2bf(f10.y);
        a1[2]=(short)f2bf(f10.z); a1[3]=(short)f2bf(f10.w);
        a1[4]=(short)f2bf(f11.x); a1[5]=(short)f2bf(f11.y);
        a1[6]=(short)f2bf(f11.z); a1[7]=(short)f2bf(f11.w);
        acc[0][0] = __builtin_amdgcn_mfma_f32_16x16x32_bf16(a0, bf[0][ks], acc[0][0], 0, 0, 0);
        acc[0][1] = __builtin_amdgcn_mfma_f32_16x16x32_bf16(a0, bf[1][ks], acc[0][1], 0, 0, 0);
        acc[1][0] = __builtin_amdgcn_mfma_f32_16x16x32_bf16(a1, bf[0][ks], acc[1][0], 0, 0, 0);
        acc[1][1] = __builtin_amdgcn_mfma_f32_16x16x32_bf16(a1, bf[1][ks], acc[1][1], 0, 0, 0);
    }
    // full-row ||x||^2: reduce across the 4 lanes sharing lo (xor 16, 32)
    p0 += __shfl_xor(p0, 16, 64); p0 += __shfl_xor(p0, 32, 64);
    p1 += __shfl_xor(p1, 16, 64); p1 += __shfl_xor(p1, 32, 64);
    if (w == 0 && hi == 0) { xsum[lo] = p0; xsum[16 + lo] = p1; }

    // per-lane bh for cols 2*lo, 2*lo+1 of this wave's band
    float bhv0 = bh[w * 32 + 2 * lo];
    float bhv1 = bh[w * 32 + 2 * lo + 1];

    // per-row partials over this wave's 32 cols (16-lane reduce)
    float spm[2][4], spb[2][4];
    #pragma unroll
    for (int rg = 0; rg < 2; ++rg)
    #pragma unroll
    for (int r = 0; r < 4; ++r) {
        float m0 = acc[rg][0][r], m1 = acc[rg][1][r];
        float pm = m0 * m0 + m1 * m1;
        float pb = m0 * bhv0 + m1 * bhv1;
        #pragma unroll
        for (int mk = 1; mk < 16; mk <<= 1) {
            pm += __shfl_xor(pm, mk, 64);
            pb += __shfl_xor(pb, mk, 64);
        }
        spm[rg][r] = pm; spb[rg][r] = pb;
    }
    if (lo == 0) {
        #pragma unroll
        for (int rg = 0; rg < 2; ++rg)
        #pragma unroll
        for (int r = 0; r < 4; ++r) {
            int row = rg * 16 + hi * 4 + r;
            part[w][row][0] = spm[rg][r];
            part[w][row][1] = spb[rg][r];
        }
    }
    __syncthreads();

    if (t < 32) {
        const int row = t;
        float pmm = part[0][row][0] + part[1][row][0] + part[2][row][0] + part[3][row][0];
        float pmb = part[0][row][1] + part[1][row][1] + part[2][row][1] + part[3][row][1];
        float pxx = xsum[row];
        float y2 = y2s;
        float x_norm  = fmaxf(sqrtf(pxx), MIN_NORM);
        float mx_norm = fmaxf(sqrtf(pmm), MIN_NORM);
        float rs = tanhf(mx_norm / x_norm * artanhf_(x_norm)) / mx_norm;
        float nres = rs * mx_norm;
        float sh = (nres > MAXNORM) ? rs * (MAXNORM / nres) : rs;
        float x2 = sh * sh * pmm;
        float xy = sh * pmb;
        float A_ = 1.f + 2.f * xy + y2;
        float B_ = 1.f - x2;
        float den = fmaxf(1.f + 2.f * xy + x2 * y2, MIN_NORM);
        float p22 = (A_ * A_ * sh * sh * pmm + 2.f * A_ * sh * B_ * pmb + B_ * B_ * y2)
                    / (den * den);
        float n2 = fmaxf(sqrtf(p22), MIN_NORM);
        float g = 1.f, n3 = n2;
        if (n2 > MAXNORM) { g = MAXNORM / n2; n3 = MAXNORM; }
        float a = artanhf_(n3);
        float s = g * (a / fmaxf(n3, MIN_NORM));
        ab[row][0] = s * A_ * sh / den;   // alpha
        ab[row][1] = s * B_ / den;        // beta
    }
    __syncthreads();

    #pragma unroll
    for (int rg = 0; rg < 2; ++rg)
    #pragma unroll
    for (int r = 0; r < 4; ++r) {
        int row = rg * 16 + hi * 4 + r;
        int grow = row0 + row;
        if (grow < N) {
            float alpha = ab[row][0], beta = ab[row][1];
            float v0 = alpha * acc[rg][0][r] + beta * bhv0;   // col 2*lo
            float v1 = alpha * acc[rg][1][r] + beta * bhv1;   // col 2*lo+1
            unsigned int pk = (unsigned int)f2bf(v0) | ((unsigned int)f2bf(v1) << 16);
            xtb[(size_t)grow * 64 + w * 16 + lo] = pk;
        }
    }
}

// ---------------------------------------------------------------------------
// CSR build: count -> scan -> fill (int2 payload)
// ---------------------------------------------------------------------------
__global__ __launch_bounds__(256) void count_kernel(
    const int* __restrict__ row, int* __restrict__ cnt, int E)
{
    int e = blockIdx.x * 256 + threadIdx.x;
    if (e < E) atomicAdd(&cnt[row[e]], 1);
}

__global__ __launch_bounds__(256) void scan1_kernel(
    const int* __restrict__ cnt, int* __restrict__ rowptr,
    int* __restrict__ bsum, int N)
{
    __shared__ int s[256];
    const int t = threadIdx.x;
    const int base = blockIdx.x * 1024 + t * 4;
    int v0 = (base + 0 < N) ? cnt[base + 0] : 0;
    int v1 = (base + 1 < N) ? cnt[base + 1] : 0;
    int v2 = (base + 2 < N) ? cnt[base + 2] : 0;
    int v3 = (base + 3 < N) ? cnt[base + 3] : 0;
    int tot = v0 + v1 + v2 + v3;
    s[t] = tot;
    __syncthreads();
    for (int off = 1; off < 256; off <<= 1) {
        int o = (t >= off) ? s[t - off] : 0;
        __syncthreads();
        s[t] += o;
        __syncthreads();
    }
    int excl = s[t] - tot;
    if (base + 0 < N) rowptr[base + 0] = excl;
    if (base + 1 < N) rowptr[base + 1] = excl + v0;
    if (base + 2 < N) rowptr[base + 2] = excl + v0 + v1;
    if (base + 3 < N) rowptr[base + 3] = excl + v0 + v1 + v2;
    if (t == 255) bsum[blockIdx.x] = s[255];
}

__global__ __launch_bounds__(256) void scan2_kernel(int* __restrict__ bsum, int nb)
{
    __shared__ int s[256];
    const int t = threadIdx.x;
    int v = (t < nb) ? bsum[t] : 0;
    s[t] = v;
    __syncthreads();
    for (int off = 1; off < 256; off <<= 1) {
        int o = (t >= off) ? s[t - off] : 0;
        __syncthreads();
        s[t] += o;
        __syncthreads();
    }
    if (t < nb) bsum[t] = s[t] - v;
}

__global__ __launch_bounds__(256) void scan3_kernel(
    int* __restrict__ rowptr, int* __restrict__ cursor,
    const int* __restrict__ bsum, int N, int E)
{
    int i = blockIdx.x * 256 + threadIdx.x;
    if (i < N) {
        int v = rowptr[i] + bsum[i >> 10];
        rowptr[i] = v;
        cursor[i] = v;
    }
    if (i == 0) rowptr[N] = E;
}

__global__ __launch_bounds__(256) void fill_kernel(
    const int* __restrict__ row, const int* __restrict__ col,
    const float* __restrict__ ew, int* __restrict__ cursor,
    int2* __restrict__ csr, int E)
{
    int e = blockIdx.x * 256 + threadIdx.x;
    if (e >= E) return;
    int pos = atomicAdd(&cursor[row[e]], 1);
    csr[pos] = make_int2(col[e], __float_as_int(ew[e]));
}

// ---------------------------------------------------------------------------
// Gather (bf16 xt): one wave per row; readlane broadcast; fused final chain.
// ---------------------------------------------------------------------------
__global__ __launch_bounds__(256) void gather_bf16(
    const unsigned int* __restrict__ xtb, const int* __restrict__ rowptr,
    const int2* __restrict__ csr, float* __restrict__ out, int N)
{
    const int wv = threadIdx.x >> 6, l = threadIdx.x & 63;
    const int r = blockIdx.x * 4 + wv;
    if (r >= N) return;
    const int beg = rowptr[r], end = rowptr[r + 1];
    float a0 = 0.f, a1 = 0.f;
    for (int base = beg; base < end; base += 64) {
        int cn = end - base; if (cn > 64) cn = 64;
        int cl = 0, wl = 0;
        if (base + l < end) { int2 p = csr[base + l]; cl = p.x; wl = p.y; }
        for (int jj = 0; jj < cn; ++jj) {
            int   c = __builtin_amdgcn_readlane(cl, jj);
            float w = __int_as_float(__builtin_amdgcn_readlane(wl, jj));
            unsigned int u = xtb[(size_t)c * 64 + l];
            float ce = __uint_as_float(u << 16);          // col 2l
            float co = __uint_as_float(u & 0xffff0000u);  // col 2l+1
            a0 = fmaf(w, ce, a0);
            a1 = fmaf(w, co, a1);
        }
    }
    float p = a0 * a0 + a1 * a1;
    for (int m = 1; m < 64; m <<= 1) p += __shfl_xor(p, m, 64);
    // expmap0 -> proj -> logmap0 -> expmap0 -> proj (scalar chain)
    float un = fmaxf(sqrtf(p), MIN_NORM);
    float th = tanhf(un);
    float s1 = th / un;
    float n1 = th;
    if (n1 > MAXNORM) { s1 *= MAXNORM / n1; n1 = MAXNORM; }
    float a  = artanhf_(n1);
    float s2 = a / fmaxf(n1, MIN_NORM);
    float ua = fmaxf(a, MIN_NORM);
    float t3 = tanhf(ua);
    float s3 = t3 / ua;
    float s4 = (t3 > MAXNORM) ? MAXNORM / t3 : 1.f;
    float s = s1 * s2 * s3 * s4;
    float2 o; o.x = s * a0; o.y = s * a1;
    ((float2*)(out + (size_t)r * 128))[l] = o;   // cols 2l, 2l+1
}

// ---------------------------------------------------------------------------
// Fallback path (ws too small): f32 linear + atomic scatter + final
// ---------------------------------------------------------------------------
#define RT 32
__global__ __launch_bounds__(256) void linear_kernel(
    const float* __restrict__ x, const float* __restrict__ W,
    const float* __restrict__ bh, float* __restrict__ xt, int N)
{
    __shared__ float xs[RT][256];
    __shared__ float ms[RT][128];
    __shared__ float bhs[128];
    __shared__ float y2s;

    const int t = threadIdx.x;
    const int row0 = blockIdx.x * RT;

    if (t < 128) bhs[t] = bh[t];
    if (t == 0) y2s = bh[128];

    #pragma unroll
    for (int i = 0; i < 8; ++i) {
        int f  = i * 256 + t;
        int r  = f >> 6;
        int c4 = f & 63;
        int gr = row0 + r; if (gr >= N) gr = N - 1;
        ((float4*)xs[r])[c4] = ((const float4*)(x + (size_t)gr * 256))[c4];
    }
    __syncthreads();

    const int j  = t & 127;
    const int r0 = (t >> 7) * 16;
    float acc[16];
    #pragma unroll
    for (int r = 0; r < 16; ++r) acc[r] = 0.f;

    const float4* Wj = (const float4*)(W + (size_t)j * 256);
    for (int k4 = 0; k4 < 64; ++k4) {
        float4 w = Wj[k4];
        #pragma unroll
        for (int r = 0; r < 16; ++r) {
            float4 xv = ((const float4*)xs[r0 + r])[k4];
            acc[r] += xv.x * w.x + xv.y * w.y + xv.z * w.z + xv.w * w.w;
        }
    }
    #pragma unroll
    for (int r = 0; r < 16; ++r) ms[r0 + r][j] = acc[r];
    __syncthreads();

    const int wv = t >> 6, l = t & 63;
    const float y2 = y2s;
    for (int rr = 0; rr < 8; ++rr) {
        int r = wv * 8 + rr;
        int grow = row0 + r;
        float m0 = ms[r][2 * l], m1 = ms[r][2 * l + 1];
        float b0 = bhs[2 * l],   b1 = bhs[2 * l + 1];
        float4 xv = ((const float4*)xs[r])[l];
        float pxx = xv.x * xv.x + xv.y * xv.y + xv.z * xv.z + xv.w * xv.w;
        float pmm = m0 * m0 + m1 * m1;
        float pmb = m0 * b0 + m1 * b1;
        for (int m = 1; m < 64; m <<= 1) {
            pxx += __shfl_xor(pxx, m, 64);
            pmm += __shfl_xor(pmm, m, 64);
            pmb += __shfl_xor(pmb, m, 64);
        }
        float x_norm  = fmaxf(sqrtf(pxx), MIN_NORM);
        float mx_norm = fmaxf(sqrtf(pmm), MIN_NORM);
        float rs = tanhf(mx_norm / x_norm * artanhf_(x_norm)) / mx_norm;
        float nres = rs * mx_norm;
        float sh = (nres > MAXNORM) ? rs * (MAXNORM / nres) : rs;
        float x2 = sh * sh * pmm;
        float xy = sh * pmb;
        float A = 1.f + 2.f * xy + y2;
        float B = 1.f - x2;
        float den = fmaxf(1.f + 2.f * xy + x2 * y2, MIN_NORM);
        float h20 = (A * sh * m0 + B * b0) / den;
        float h21 = (A * sh * m1 + B * b1) / den;
        float p22 = h20 * h20 + h21 * h21;
        for (int m = 1; m < 64; m <<= 1) p22 += __shfl_xor(p22, m, 64);
        float n2 = fmaxf(sqrtf(p22), MIN_NORM);
        float g = 1.f, n3 = n2;
        if (n2 > MAXNORM) { g = MAXNORM / n2; n3 = MAXNORM; }
        float a = artanhf_(n3);
        float s = g * (a / fmaxf(n3, MIN_NORM));
        if (grow < N) {
            float2 o; o.x = s * h20; o.y = s * h21;
            ((float2*)(xt + (size_t)grow * 128))[l] = o;
        }
    }
}

__global__ __launch_bounds__(256) void scatter_kernel(
    const float* __restrict__ xt, const int* __restrict__ row,
    const int* __restrict__ col, const float* __restrict__ ew,
    float* __restrict__ agg, int E)
{
    long g = (long)blockIdx.x * blockDim.x + threadIdx.x;
    long e = g >> 5;
    int  l = (int)(g & 31);
    if (e >= E) return;
    int r = row[e], c = col[e];
    float wv = ew[e];
    float4 v = ((const float4*)(xt + (size_t)c * 128))[l];
    float* dst = agg + (size_t)r * 128 + l * 4;
    atomicAdd(dst + 0, v.x * wv);
    atomicAdd(dst + 1, v.y * wv);
    atomicAdd(dst + 2, v.z * wv);
    atomicAdd(dst + 3, v.w * wv);
}

__global__ __launch_bounds__(256) void final_kernel(float* __restrict__ io, int N) {
    const int wv = threadIdx.x >> 6, l = threadIdx.x & 63;
    const int r = blockIdx.x * 4 + wv;
    if (r >= N) return;
    float2 v = ((const float2*)(io + (size_t)r * 128))[l];
    float p = v.x * v.x + v.y * v.y;
    for (int m = 1; m < 64; m <<= 1) p += __shfl_xor(p, m, 64);
    float un = fmaxf(sqrtf(p), MIN_NORM);
    float th = tanhf(un);
    float s1 = th / un;
    float n1 = th;
    if (n1 > MAXNORM) { s1 *= MAXNORM / n1; n1 = MAXNORM; }
    float a  = artanhf_(n1);
    float s2 = a / fmaxf(n1, MIN_NORM);
    float ua = fmaxf(a, MIN_NORM);
    float t3 = tanhf(ua);
    float s3 = t3 / ua;
    float s4 = (t3 > MAXNORM) ? MAXNORM / t3 : 1.f;
    float s = s1 * s2 * s3 * s4;
    float2 o; o.x = s * v.x; o.y = s * v.y;
    ((float2*)(io + (size_t)r * 128))[l] = o;
}

// ---------------------------------------------------------------------------
extern "C" void kernel_launch(void* const* d_in, const int* in_sizes, int n_in,
                              void* d_out, int out_size, void* d_ws, size_t ws_size,
                              hipStream_t stream) {
    const float* x    = (const float*)d_in[0];
    const int*   ei   = (const int*)d_in[1];
    const float* ew   = (const float*)d_in[2];
    const float* W    = (const float*)d_in[3];
    const float* bias = (const float*)d_in[4];

    const int N = in_sizes[0] / 256;
    const int E = in_sizes[2];
    float* out = (float*)d_out;
    char*  ws  = (char*)d_ws;

    // --- new layout (bf16 path) ---
    size_t off = 0;
    float* bh = (float*)(ws + off);                   off += 256 * sizeof(float);
    unsigned short* wb = (unsigned short*)(ws + off); off += 32768 * sizeof(unsigned short);
    unsigned int* xtb = (unsigned int*)(ws + off);    off += (size_t)N * 64 * sizeof(unsigned int);
    int* rowptr = (int*)(ws + off);                   off += ((size_t)N + 16) * sizeof(int);
    int* cursor = (int*)(ws + off);                   off += (size_t)N * sizeof(int);
    int* bsum   = (int*)(ws + off);                   off += 4096 * sizeof(int);
    int2* csr   = (int2*)(ws + off);                  off += (size_t)E * sizeof(int2);
    const size_t need_new = off;

    // --- fallback layout (f32, atomic scatter) ---
    size_t off2 = 0;
    float* bh2 = (float*)(ws + off2);          off2 += 256 * sizeof(float);
    float* xt2 = (float*)(ws + off2);          off2 += (size_t)N * 128 * sizeof(float);
    const size_t need_old = off2;

    const int nb = (N + 1023) / 1024;          // <= 256 for N <= 262144

    if (ws_size >= need_new) {
        bias_kernel<<<1, 64, 0, stream>>>(bias, bh);
        prep_w<<<128, 256, 0, stream>>>(W, wb);
        linear_mfma<<<(N + 31) / 32, 256, 0, stream>>>(x, wb, bh, xtb, N);
        hipMemsetAsync(rowptr, 0, (size_t)N * sizeof(int), stream);
        count_kernel<<<(E + 255) / 256, 256, 0, stream>>>(ei, rowptr, E);
        scan1_kernel<<<nb, 256, 0, stream>>>(rowptr, rowptr, bsum, N);
        scan2_kernel<<<1, 256, 0, stream>>>(bsum, nb);
        scan3_kernel<<<(N + 255) / 256, 256, 0, stream>>>(rowptr, cursor, bsum, N, E);
        fill_kernel<<<(E + 255) / 256, 256, 0, stream>>>(
            ei, ei + E, ew, cursor, csr, E);
        gather_bf16<<<(N + 3) / 4, 256, 0, stream>>>(
            xtb, rowptr, csr, out, N);
    } else {
        bias_kernel<<<1, 64, 0, stream>>>(bias, bh2);
        linear_kernel<<<(N + RT - 1) / RT, 256, 0, stream>>>(x, W, bh2, xt2, N);
        hipMemsetAsync(out, 0, (size_t)N * 128 * sizeof(float), stream);
        long threads = (long)E * 32;
        scatter_kernel<<<(unsigned)((threads + 255) / 256), 256, 0, stream>>>(
            xt2, ei, ei + E, ew, out, E);
        final_kernel<<<(N + 3) / 4, 256, 0, stream>>>(out, N);
    }
}